// Round 11
// baseline (123.226 us; speedup 1.0000x reference)
//
#include <hip/hip_runtime.h>
#include <hip/hip_fp16.h>
#include <math.h>

#define Vn 3
#define Bn 2
#define Cn 16
#define Hn 128
#define Wn 128
#define Dn 32
#define HWn (Hn*Wn)
#define PX 16         // pixels per block in fused agg kernel

typedef float v4f __attribute__((ext_vector_type(4)));

// featH layout: (V*B, 2, H*W, 8) halfs — split-half planes (16B records).

// load 8 halfs (16B) -> 8 floats
__device__ __forceinline__ void loadC8(float* r, const __half* p) {
    union { v4f f; __half2 h[4]; } u;
    u.f = *(const v4f*)p;
    #pragma unroll
    for (int j = 0; j < 4; j++) {
        float2 a = __half22float2(u.h[j]);
        r[2*j] = a.x; r[2*j+1] = a.y;
    }
}

// non-temporal variant for zero-reuse random gathers (skip L1 allocation)
__device__ __forceinline__ void loadC8nt(float* r, const __half* p) {
    union { v4f f; __half2 h[4]; } u;
    u.f = __builtin_nontemporal_load((const v4f*)p);
    #pragma unroll
    for (int j = 0; j < 4; j++) {
        float2 a = __half22float2(u.h[j]);
        r[2*j] = a.x; r[2*j+1] = a.y;
    }
}

// ---------------------------------------------------------------------------
// Stage 0: transpose features (V,B,C,H,W) fp32 -> split-half fp16 planes
//          + block 0 threads 0..3 compute the projection matrices
// ---------------------------------------------------------------------------
__global__ void transpose_kernel(const float* __restrict__ feat,
                                 __half* __restrict__ featH,
                                 const float* __restrict__ intr,
                                 const float* __restrict__ c2w,
                                 float* __restrict__ proj) {
    int idx = blockIdx.x * blockDim.x + threadIdx.x;   // vb*HWn + p
    if (idx < Vn * Bn * HWn) {
        int p  = idx % HWn;
        int vb = idx / HWn;
        const float* src = feat + (size_t)vb * Cn * HWn + p;
        union { float4 f[2]; __half h[16]; } u;
        #pragma unroll
        for (int c = 0; c < Cn; c++) u.h[c] = __float2half(src[(size_t)c * HWn]);
        __half* base = featH + (size_t)vb * 2 * HWn * 8;
        *(float4*)(base + (size_t)p * 8)         = u.f[0];   // ch 0-7
        *(float4*)(base + ((size_t)HWn + p) * 8) = u.f[1];   // ch 8-15
    }

    if (blockIdx.x == 0 && threadIdx.x < (Vn - 1) * Bn) {
        int t  = threadIdx.x;
        int vi = t / Bn;
        int b  = t % Bn;
        int v  = vi + 1;

        const float* Ks = intr + (v * Bn + b) * 9;
        const float* Cs = c2w  + (v * Bn + b) * 16;
        const float* Kr = intr + (0 * Bn + b) * 9;
        const float* Cr = c2w  + (0 * Bn + b) * 16;

        float Ms[9], ms[3], Mr[9], mr[3];
        for (int which = 0; which < 2; which++) {
            const float* K = which ? Kr : Ks;
            const float* C = which ? Cr : Cs;
            float* M  = which ? Mr : Ms;
            float* mv = which ? mr : ms;
            float R[9], tt[3];
            for (int i = 0; i < 3; i++) {
                for (int j = 0; j < 3; j++) R[i*3+j] = C[i*4+j];
                tt[i] = C[i*4+3];
            }
            float tw[3];
            for (int i = 0; i < 3; i++)
                tw[i] = -(R[0*3+i]*tt[0] + R[1*3+i]*tt[1] + R[2*3+i]*tt[2]);
            for (int i = 0; i < 3; i++)
                for (int j = 0; j < 3; j++)
                    M[i*3+j] = K[i*3+0]*R[j*3+0] + K[i*3+1]*R[j*3+1] + K[i*3+2]*R[j*3+2];
            for (int i = 0; i < 3; i++)
                mv[i] = K[i*3+0]*tw[0] + K[i*3+1]*tw[1] + K[i*3+2]*tw[2] + tw[i];
        }

        float a = Mr[0], bb = Mr[1], c = Mr[2];
        float d = Mr[3], e  = Mr[4], f = Mr[5];
        float g = Mr[6], h  = Mr[7], i2 = Mr[8];
        float A_ = (e*i2 - f*h), B_ = (f*g - d*i2), C_ = (d*h - e*g);
        float det = a*A_ + bb*B_ + c*C_;
        float id = 1.0f / det;
        float inv[9];
        inv[0] = A_*id;            inv[1] = (c*h - bb*i2)*id;  inv[2] = (bb*f - c*e)*id;
        inv[3] = B_*id;            inv[4] = (a*i2 - c*g)*id;   inv[5] = (c*d - a*f)*id;
        inv[6] = C_*id;            inv[7] = (bb*g - a*h)*id;   inv[8] = (a*e - bb*d)*id;

        float rot[9], trans[3];
        for (int r = 0; r < 3; r++)
            for (int cc = 0; cc < 3; cc++)
                rot[r*3+cc] = Ms[r*3+0]*inv[0*3+cc] + Ms[r*3+1]*inv[1*3+cc] + Ms[r*3+2]*inv[2*3+cc];
        for (int r = 0; r < 3; r++)
            trans[r] = ms[r] - (rot[r*3+0]*mr[0] + rot[r*3+1]*mr[1] + rot[r*3+2]*mr[2]);

        float* o = proj + t * 12;
        for (int k = 0; k < 9; k++) o[k] = rot[k];
        for (int k = 0; k < 3; k++) o[9+k] = trans[k];
    }
}

// ---------------------------------------------------------------------------
// Stage 2: cost volume (B,D,H,W). Depth-major lanes (half-wave = one pixel,
// ref loads broadcast). Random depth map => random gather: nt loads to avoid
// L1 pollution; structure otherwise at its measured plateau.
// ---------------------------------------------------------------------------
__global__ void __launch_bounds__(256)
cost_kernel(const __half* __restrict__ featH,
            const float* __restrict__ depth,
            const float* __restrict__ proj,
            float* __restrict__ cv) {
    int idx = blockIdx.x * blockDim.x + threadIdx.x;   // ((b*H+y)*W+x)*D + d
    if (idx >= Bn * HWn * Dn) return;
    int d = idx & (Dn - 1);
    int x = (idx >> 5)  & (Wn - 1);
    int y = (idx >> 12) & (Hn - 1);
    int b = idx >> 19;

    const int pix = y * Wn + x;
    float dep = depth[(size_t)(b * Dn + d) * HWn + pix];

    float ref[Cn];
    const __half* rbase = featH + (size_t)b * 2 * HWn * 8;
    loadC8(ref,     rbase + (size_t)pix * 8);
    loadC8(ref + 8, rbase + ((size_t)HWn + pix) * 8);

    const float fxp = (float)x, fyp = (float)y;

    float cum[Cn];
    #pragma unroll
    for (int c = 0; c < Cn; c++) cum[c] = 0.0f;
    float smin = 3.402823e38f;

    #pragma unroll
    for (int vi = 0; vi < Vn - 1; vi++) {
        const float* P = proj + (vi * Bn + b) * 12;
        float rx = P[0]*fxp + P[1]*fyp + P[2];
        float ry = P[3]*fxp + P[4]*fyp + P[5];
        float rz = P[6]*fxp + P[7]*fyp + P[8];

        float px = rx * dep + P[9];
        float py = ry * dep + P[10];
        float pz = rz * dep + P[11];
        float inz = 1.0f / pz;
        float sx = px * inz * ((float)Wn / (float)(Wn - 1)) - 0.5f;
        float sy = py * inz * ((float)Hn / (float)(Hn - 1)) - 0.5f;

        float x0f = floorf(sx), y0f = floorf(sy);
        float fx = sx - x0f, fy = sy - y0f;
        int x0 = (int)x0f, y0 = (int)y0f;
        int x1 = x0 + 1, y1 = y0 + 1;
        bool vx0 = (x0 >= 0) && (x0 < Wn);
        bool vx1 = (x1 >= 0) && (x1 < Wn);
        bool vy0 = (y0 >= 0) && (y0 < Hn);
        bool vy1 = (y1 >= 0) && (y1 < Hn);
        int xc0 = min(max(x0, 0), Wn - 1), xc1 = min(max(x1, 0), Wn - 1);
        int yc0 = min(max(y0, 0), Hn - 1), yc1 = min(max(y1, 0), Hn - 1);
        float m00 = (vx0 && vy0) ? (1.0f - fx) * (1.0f - fy) : 0.0f;
        float m01 = (vx1 && vy0) ? fx * (1.0f - fy) : 0.0f;
        float m10 = (vx0 && vy1) ? (1.0f - fx) * fy : 0.0f;
        float m11 = (vx1 && vy1) ? fx * fy : 0.0f;

        const __half* sf = featH + (size_t)((vi + 1) * Bn + b) * 2 * HWn * 8;
        int p00 = (yc0 * Wn + xc0) * 8;
        int p01 = (yc0 * Wn + xc1) * 8;
        int p10 = (yc1 * Wn + xc0) * 8;
        int p11 = (yc1 * Wn + xc1) * 8;
        const int hoff = HWn * 8;

        float s = 0.0f;
        #pragma unroll
        for (int h = 0; h < 2; h++) {
            float t00[8], t01[8], t10[8], t11[8];
            loadC8nt(t00, sf + p00 + h * hoff);
            loadC8nt(t01, sf + p01 + h * hoff);
            loadC8nt(t10, sf + p10 + h * hoff);
            loadC8nt(t11, sf + p11 + h * hoff);
            #pragma unroll
            for (int j = 0; j < 8; j++) {
                int c = h * 8 + j;
                float val = m00 * t00[j] + m01 * t01[j] + m10 * t10[j] + m11 * t11[j];
                cum[c] += val;
                float df = ref[c] - cum[c];
                s += df * df;
            }
        }
        smin = fminf(smin, s);
    }
    cv[(size_t)(b * Dn + d) * HWn + pix] = sqrtf(smin);
}

// ---------------------------------------------------------------------------
// Stage 3+4+5 fused. agg softmax(25) is SINGLE-PASS: |dn-ctr| <= 10 so
// exp args bounded (e^10 = 2.2e4) — max-subtraction unnecessary and the
// ratio is identical in fp32. Final softmax over D keeps max-subtraction
// (agg values can reach ~100).
// ---------------------------------------------------------------------------
__global__ void __launch_bounds__(256)
aggfinal_kernel(const float* __restrict__ cv,
                const float* __restrict__ depth,
                const __half* __restrict__ featH,
                float* __restrict__ out) {
    __shared__ float sd[Dn][5][PX + 4];        // depth neighborhood
    __shared__ float sc[Dn][5][PX + 4];        // cost neighborhood
    __shared__ float4 sfeatv[5][PX + 4][2];    // view-0 feature halo (fp16)
    __shared__ float swf[25][PX];              // w_feat
    __shared__ float sagg[Dn][PX];             // aggregated cost

    int bi = blockIdx.x;
    int xt = bi % (Wn / PX);
    int y  = (bi / (Wn / PX)) % Hn;
    int b  = bi / (Hn * (Wn / PX));
    int x0 = xt * PX;
    int tid = threadIdx.x;

    const int NS = Dn * 5 * (PX + 4);          // 3200
    for (int s = tid; s < NS; s += 256) {
        int d  = s / (5 * (PX + 4));
        int r  = s % (5 * (PX + 4));
        int ny = r / (PX + 4);
        int nx = r % (PX + 4);
        int gy = y - 2 + ny;
        int gx = x0 - 2 + nx;
        float dv = 0.0f, cvv = 0.0f;
        if (gy >= 0 && gy < Hn && gx >= 0 && gx < Wn) {
            size_t off = (size_t)(b * Dn + d) * HWn + gy * Wn + gx;
            dv  = depth[off];
            cvv = cv[off];
        }
        sd[d][ny][nx] = dv;
        sc[d][ny][nx] = cvv;
    }
    const __half* fb = featH + (size_t)b * 2 * HWn * 8;
    for (int s = tid; s < 5 * (PX + 4); s += 256) {
        int ny = s / (PX + 4);
        int nx = s % (PX + 4);
        int gy = y - 2 + ny;
        int gx = x0 - 2 + nx;
        if (gy >= 0 && gy < Hn && gx >= 0 && gx < Wn) {
            sfeatv[ny][nx][0] = *(const float4*)(fb + (size_t)(gy * Wn + gx) * 8);
            sfeatv[ny][nx][1] = *(const float4*)(fb + ((size_t)HWn + gy * Wn + gx) * 8);
        } else {
            float4 z = make_float4(0.f, 0.f, 0.f, 0.f);
            sfeatv[ny][nx][0] = z;
            sfeatv[ny][nx][1] = z;
        }
    }
    __syncthreads();

    for (int s = tid; s < 25 * PX; s += 256) {
        int k   = s / PX;
        int xi2 = s % PX;
        const __half2* ctrp = (const __half2*)&sfeatv[2][xi2 + 2][0];
        const __half2* nbp  = (const __half2*)&sfeatv[k / 5][xi2 + (k % 5)][0];
        float acc = 0.0f;
        #pragma unroll
        for (int j = 0; j < 8; j++) {
            float2 a = __half22float2(nbp[j]);
            float2 c = __half22float2(ctrp[j]);
            float dx0 = a.x - c.x, dy0 = a.y - c.y;
            acc += dx0 * dx0 + dy0 * dy0;
        }
        swf[k][xi2] = sqrtf(acc);
    }
    __syncthreads();

    // agg: Dn*PX = 512 tasks, 2 per thread, single pass (no max needed)
    #pragma unroll
    for (int q = 0; q < 2; q++) {
        int task = tid + q * 256;
        int xi = task % PX;
        int d  = task / PX;

        float ctr = sd[d][2][xi + 2];
        float den = 0.0f, num = 0.0f;
        #pragma unroll
        for (int k = 0; k < 25; k++) {
            float dn = sd[d][k / 5][xi + k % 5];
            float e = __expf(fabsf(dn - ctr));
            den += e;
            num += sc[d][k / 5][xi + k % 5] * e * swf[k][xi];
        }
        sagg[d][xi] = num / den;
    }
    __syncthreads();

    if (tid < PX) {
        int p = tid;
        float m = -3.402823e38f;
        #pragma unroll
        for (int dd = 0; dd < Dn; dd++)
            m = fmaxf(m, sagg[dd][p]);
        float dn2 = 0.0f, nm2 = 0.0f;
        #pragma unroll
        for (int dd = 0; dd < Dn; dd++) {
            float e = __expf(sagg[dd][p] - m);
            dn2 += e;
            nm2 += e * sd[dd][2][p + 2];
        }
        out[(size_t)(b * Hn + y) * Wn + x0 + p] = nm2 / dn2;
    }
}

// ---------------------------------------------------------------------------
extern "C" void kernel_launch(void* const* d_in, const int* in_sizes, int n_in,
                              void* d_out, int out_size, void* d_ws, size_t ws_size,
                              hipStream_t stream) {
    const float* feat  = (const float*)d_in[0];   // (V,B,C,H,W)
    const float* intr  = (const float*)d_in[1];   // (V,B,3,3)
    const float* c2w   = (const float*)d_in[2];   // (V,B,4,4)
    const float* depth = (const float*)d_in[3];   // (B,D,H,W)
    float* out = (float*)d_out;                   // (B,H,W)

    float* ws    = (float*)d_ws;
    float* proj  = ws;                                        // 64 floats
    __half* featH = (__half*)(ws + 64);                       // V*B*2*HW*8 halfs = 3MB
    float* cv    = ws + 64 + (Vn * Bn * HWn * Cn) / 2;        // B*D*HW floats

    int n_tr = Vn * Bn * HWn;
    transpose_kernel<<<(n_tr + 255) / 256, 256, 0, stream>>>(feat, featH, intr, c2w, proj);

    int n_cost = Bn * HWn * Dn;
    cost_kernel<<<(n_cost + 255) / 256, 256, 0, stream>>>(featH, depth, proj, cv);

    int n_blk = Bn * Hn * (Wn / PX);
    aggfinal_kernel<<<n_blk, 256, 0, stream>>>(cv, depth, featH, out);
}

// Round 12
// 113.514 us; speedup vs baseline: 1.0856x; 1.0856x over previous
//
#include <hip/hip_runtime.h>
#include <hip/hip_fp16.h>
#include <math.h>

#define Vn 3
#define Bn 2
#define Cn 16
#define Hn 128
#define Wn 128
#define Dn 32
#define HWn (Hn*Wn)
#define PX 16         // pixels per block in fused agg kernel

// featH layout: (V*B, 2, H*W, 8) halfs — split-half planes (16B records).

// load 8 halfs (16B) -> 8 floats
__device__ __forceinline__ void loadC8(float* r, const __half* p) {
    union { float4 f; __half2 h[4]; } u;
    u.f = *(const float4*)p;
    #pragma unroll
    for (int j = 0; j < 4; j++) {
        float2 a = __half22float2(u.h[j]);
        r[2*j] = a.x; r[2*j+1] = a.y;
    }
}

// ---------------------------------------------------------------------------
// Stage 0: transpose features (V,B,C,H,W) fp32 -> split-half fp16 planes
//          + block 0 threads 0..3 compute the projection matrices
// ---------------------------------------------------------------------------
__global__ void transpose_kernel(const float* __restrict__ feat,
                                 __half* __restrict__ featH,
                                 const float* __restrict__ intr,
                                 const float* __restrict__ c2w,
                                 float* __restrict__ proj) {
    int idx = blockIdx.x * blockDim.x + threadIdx.x;   // vb*HWn + p
    if (idx < Vn * Bn * HWn) {
        int p  = idx % HWn;
        int vb = idx / HWn;
        const float* src = feat + (size_t)vb * Cn * HWn + p;
        union { float4 f[2]; __half h[16]; } u;
        #pragma unroll
        for (int c = 0; c < Cn; c++) u.h[c] = __float2half(src[(size_t)c * HWn]);
        __half* base = featH + (size_t)vb * 2 * HWn * 8;
        *(float4*)(base + (size_t)p * 8)         = u.f[0];   // ch 0-7
        *(float4*)(base + ((size_t)HWn + p) * 8) = u.f[1];   // ch 8-15
    }

    if (blockIdx.x == 0 && threadIdx.x < (Vn - 1) * Bn) {
        int t  = threadIdx.x;
        int vi = t / Bn;
        int b  = t % Bn;
        int v  = vi + 1;

        const float* Ks = intr + (v * Bn + b) * 9;
        const float* Cs = c2w  + (v * Bn + b) * 16;
        const float* Kr = intr + (0 * Bn + b) * 9;
        const float* Cr = c2w  + (0 * Bn + b) * 16;

        float Ms[9], ms[3], Mr[9], mr[3];
        for (int which = 0; which < 2; which++) {
            const float* K = which ? Kr : Ks;
            const float* C = which ? Cr : Cs;
            float* M  = which ? Mr : Ms;
            float* mv = which ? mr : ms;
            float R[9], tt[3];
            for (int i = 0; i < 3; i++) {
                for (int j = 0; j < 3; j++) R[i*3+j] = C[i*4+j];
                tt[i] = C[i*4+3];
            }
            float tw[3];
            for (int i = 0; i < 3; i++)
                tw[i] = -(R[0*3+i]*tt[0] + R[1*3+i]*tt[1] + R[2*3+i]*tt[2]);
            for (int i = 0; i < 3; i++)
                for (int j = 0; j < 3; j++)
                    M[i*3+j] = K[i*3+0]*R[j*3+0] + K[i*3+1]*R[j*3+1] + K[i*3+2]*R[j*3+2];
            for (int i = 0; i < 3; i++)
                mv[i] = K[i*3+0]*tw[0] + K[i*3+1]*tw[1] + K[i*3+2]*tw[2] + tw[i];
        }

        float a = Mr[0], bb = Mr[1], c = Mr[2];
        float d = Mr[3], e  = Mr[4], f = Mr[5];
        float g = Mr[6], h  = Mr[7], i2 = Mr[8];
        float A_ = (e*i2 - f*h), B_ = (f*g - d*i2), C_ = (d*h - e*g);
        float det = a*A_ + bb*B_ + c*C_;
        float id = 1.0f / det;
        float inv[9];
        inv[0] = A_*id;            inv[1] = (c*h - bb*i2)*id;  inv[2] = (bb*f - c*e)*id;
        inv[3] = B_*id;            inv[4] = (a*i2 - c*g)*id;   inv[5] = (c*d - a*f)*id;
        inv[6] = C_*id;            inv[7] = (bb*g - a*h)*id;   inv[8] = (a*e - bb*d)*id;

        float rot[9], trans[3];
        for (int r = 0; r < 3; r++)
            for (int cc = 0; cc < 3; cc++)
                rot[r*3+cc] = Ms[r*3+0]*inv[0*3+cc] + Ms[r*3+1]*inv[1*3+cc] + Ms[r*3+2]*inv[2*3+cc];
        for (int r = 0; r < 3; r++)
            trans[r] = ms[r] - (rot[r*3+0]*mr[0] + rot[r*3+1]*mr[1] + rot[r*3+2]*mr[2]);

        float* o = proj + t * 12;
        for (int k = 0; k < 9; k++) o[k] = rot[k];
        for (int k = 0; k < 3; k++) o[9+k] = trans[k];
    }
}

// ---------------------------------------------------------------------------
// Stage 2: cost volume (B,D,H,W). Depth-major lanes (half-wave = one pixel,
// ref loads broadcast). Corner gathers have heavy CROSS-THREAD reuse
// (~128 threads/pixel) -> plain loads so L1 captures it (nt regressed, R10).
// ---------------------------------------------------------------------------
__global__ void __launch_bounds__(256)
cost_kernel(const __half* __restrict__ featH,
            const float* __restrict__ depth,
            const float* __restrict__ proj,
            float* __restrict__ cv) {
    int idx = blockIdx.x * blockDim.x + threadIdx.x;   // ((b*H+y)*W+x)*D + d
    if (idx >= Bn * HWn * Dn) return;
    int d = idx & (Dn - 1);
    int x = (idx >> 5)  & (Wn - 1);
    int y = (idx >> 12) & (Hn - 1);
    int b = idx >> 19;

    const int pix = y * Wn + x;
    float dep = depth[(size_t)(b * Dn + d) * HWn + pix];

    float ref[Cn];
    const __half* rbase = featH + (size_t)b * 2 * HWn * 8;
    loadC8(ref,     rbase + (size_t)pix * 8);
    loadC8(ref + 8, rbase + ((size_t)HWn + pix) * 8);

    const float fxp = (float)x, fyp = (float)y;

    float cum[Cn];
    #pragma unroll
    for (int c = 0; c < Cn; c++) cum[c] = 0.0f;
    float smin = 3.402823e38f;

    #pragma unroll
    for (int vi = 0; vi < Vn - 1; vi++) {
        const float* P = proj + (vi * Bn + b) * 12;
        float rx = P[0]*fxp + P[1]*fyp + P[2];
        float ry = P[3]*fxp + P[4]*fyp + P[5];
        float rz = P[6]*fxp + P[7]*fyp + P[8];

        float px = rx * dep + P[9];
        float py = ry * dep + P[10];
        float pz = rz * dep + P[11];
        float inz = 1.0f / pz;
        float sx = px * inz * ((float)Wn / (float)(Wn - 1)) - 0.5f;
        float sy = py * inz * ((float)Hn / (float)(Hn - 1)) - 0.5f;

        float x0f = floorf(sx), y0f = floorf(sy);
        float fx = sx - x0f, fy = sy - y0f;
        int x0 = (int)x0f, y0 = (int)y0f;
        int x1 = x0 + 1, y1 = y0 + 1;
        bool vx0 = (x0 >= 0) && (x0 < Wn);
        bool vx1 = (x1 >= 0) && (x1 < Wn);
        bool vy0 = (y0 >= 0) && (y0 < Hn);
        bool vy1 = (y1 >= 0) && (y1 < Hn);
        int xc0 = min(max(x0, 0), Wn - 1), xc1 = min(max(x1, 0), Wn - 1);
        int yc0 = min(max(y0, 0), Hn - 1), yc1 = min(max(y1, 0), Hn - 1);
        float m00 = (vx0 && vy0) ? (1.0f - fx) * (1.0f - fy) : 0.0f;
        float m01 = (vx1 && vy0) ? fx * (1.0f - fy) : 0.0f;
        float m10 = (vx0 && vy1) ? (1.0f - fx) * fy : 0.0f;
        float m11 = (vx1 && vy1) ? fx * fy : 0.0f;

        const __half* sf = featH + (size_t)((vi + 1) * Bn + b) * 2 * HWn * 8;
        int p00 = (yc0 * Wn + xc0) * 8;
        int p01 = (yc0 * Wn + xc1) * 8;
        int p10 = (yc1 * Wn + xc0) * 8;
        int p11 = (yc1 * Wn + xc1) * 8;
        const int hoff = HWn * 8;

        float s = 0.0f;
        #pragma unroll
        for (int h = 0; h < 2; h++) {
            float t00[8], t01[8], t10[8], t11[8];
            loadC8(t00, sf + p00 + h * hoff);
            loadC8(t01, sf + p01 + h * hoff);
            loadC8(t10, sf + p10 + h * hoff);
            loadC8(t11, sf + p11 + h * hoff);
            #pragma unroll
            for (int j = 0; j < 8; j++) {
                int c = h * 8 + j;
                float val = m00 * t00[j] + m01 * t01[j] + m10 * t10[j] + m11 * t11[j];
                cum[c] += val;
                float df = ref[c] - cum[c];
                s += df * df;
            }
        }
        smin = fminf(smin, s);
    }
    cv[(size_t)(b * Dn + d) * HWn + pix] = sqrtf(smin);
}

// ---------------------------------------------------------------------------
// Stage 3+4+5 fused. agg softmax(25) single-pass: |dn-ctr| <= 10 so exp
// bounded (e^10=2.2e4) — identical ratio in fp32. Final softmax over D
// keeps max-subtraction.
// ---------------------------------------------------------------------------
__global__ void __launch_bounds__(256)
aggfinal_kernel(const float* __restrict__ cv,
                const float* __restrict__ depth,
                const __half* __restrict__ featH,
                float* __restrict__ out) {
    __shared__ float sd[Dn][5][PX + 4];        // depth neighborhood
    __shared__ float sc[Dn][5][PX + 4];        // cost neighborhood
    __shared__ float4 sfeatv[5][PX + 4][2];    // view-0 feature halo (fp16)
    __shared__ float swf[25][PX];              // w_feat
    __shared__ float sagg[Dn][PX];             // aggregated cost

    int bi = blockIdx.x;
    int xt = bi % (Wn / PX);
    int y  = (bi / (Wn / PX)) % Hn;
    int b  = bi / (Hn * (Wn / PX));
    int x0 = xt * PX;
    int tid = threadIdx.x;

    const int NS = Dn * 5 * (PX + 4);          // 3200
    for (int s = tid; s < NS; s += 256) {
        int d  = s / (5 * (PX + 4));
        int r  = s % (5 * (PX + 4));
        int ny = r / (PX + 4);
        int nx = r % (PX + 4);
        int gy = y - 2 + ny;
        int gx = x0 - 2 + nx;
        float dv = 0.0f, cvv = 0.0f;
        if (gy >= 0 && gy < Hn && gx >= 0 && gx < Wn) {
            size_t off = (size_t)(b * Dn + d) * HWn + gy * Wn + gx;
            dv  = depth[off];
            cvv = cv[off];
        }
        sd[d][ny][nx] = dv;
        sc[d][ny][nx] = cvv;
    }
    const __half* fb = featH + (size_t)b * 2 * HWn * 8;
    for (int s = tid; s < 5 * (PX + 4); s += 256) {
        int ny = s / (PX + 4);
        int nx = s % (PX + 4);
        int gy = y - 2 + ny;
        int gx = x0 - 2 + nx;
        if (gy >= 0 && gy < Hn && gx >= 0 && gx < Wn) {
            sfeatv[ny][nx][0] = *(const float4*)(fb + (size_t)(gy * Wn + gx) * 8);
            sfeatv[ny][nx][1] = *(const float4*)(fb + ((size_t)HWn + gy * Wn + gx) * 8);
        } else {
            float4 z = make_float4(0.f, 0.f, 0.f, 0.f);
            sfeatv[ny][nx][0] = z;
            sfeatv[ny][nx][1] = z;
        }
    }
    __syncthreads();

    for (int s = tid; s < 25 * PX; s += 256) {
        int k   = s / PX;
        int xi2 = s % PX;
        const __half2* ctrp = (const __half2*)&sfeatv[2][xi2 + 2][0];
        const __half2* nbp  = (const __half2*)&sfeatv[k / 5][xi2 + (k % 5)][0];
        float acc = 0.0f;
        #pragma unroll
        for (int j = 0; j < 8; j++) {
            float2 a = __half22float2(nbp[j]);
            float2 c = __half22float2(ctrp[j]);
            float dx0 = a.x - c.x, dy0 = a.y - c.y;
            acc += dx0 * dx0 + dy0 * dy0;
        }
        swf[k][xi2] = sqrtf(acc);
    }
    __syncthreads();

    // agg: Dn*PX = 512 tasks, 2 per thread, single pass (no max needed)
    #pragma unroll
    for (int q = 0; q < 2; q++) {
        int task = tid + q * 256;
        int xi = task % PX;
        int d  = task / PX;

        float ctr = sd[d][2][xi + 2];
        float den = 0.0f, num = 0.0f;
        #pragma unroll
        for (int k = 0; k < 25; k++) {
            float dn = sd[d][k / 5][xi + k % 5];
            float e = __expf(fabsf(dn - ctr));
            den += e;
            num += sc[d][k / 5][xi + k % 5] * e * swf[k][xi];
        }
        sagg[d][xi] = num / den;
    }
    __syncthreads();

    if (tid < PX) {
        int p = tid;
        float m = -3.402823e38f;
        #pragma unroll
        for (int dd = 0; dd < Dn; dd++)
            m = fmaxf(m, sagg[dd][p]);
        float dn2 = 0.0f, nm2 = 0.0f;
        #pragma unroll
        for (int dd = 0; dd < Dn; dd++) {
            float e = __expf(sagg[dd][p] - m);
            dn2 += e;
            nm2 += e * sd[dd][2][p + 2];
        }
        out[(size_t)(b * Hn + y) * Wn + x0 + p] = nm2 / dn2;
    }
}

// ---------------------------------------------------------------------------
extern "C" void kernel_launch(void* const* d_in, const int* in_sizes, int n_in,
                              void* d_out, int out_size, void* d_ws, size_t ws_size,
                              hipStream_t stream) {
    const float* feat  = (const float*)d_in[0];   // (V,B,C,H,W)
    const float* intr  = (const float*)d_in[1];   // (V,B,3,3)
    const float* c2w   = (const float*)d_in[2];   // (V,B,4,4)
    const float* depth = (const float*)d_in[3];   // (B,D,H,W)
    float* out = (float*)d_out;                   // (B,H,W)

    float* ws    = (float*)d_ws;
    float* proj  = ws;                                        // 64 floats
    __half* featH = (__half*)(ws + 64);                       // V*B*2*HW*8 halfs = 3MB
    float* cv    = ws + 64 + (Vn * Bn * HWn * Cn) / 2;        // B*D*HW floats

    int n_tr = Vn * Bn * HWn;
    transpose_kernel<<<(n_tr + 255) / 256, 256, 0, stream>>>(feat, featH, intr, c2w, proj);

    int n_cost = Bn * HWn * Dn;
    cost_kernel<<<(n_cost + 255) / 256, 256, 0, stream>>>(featH, depth, proj, cv);

    int n_blk = Bn * Hn * (Wn / PX);
    aggfinal_kernel<<<n_blk, 256, 0, stream>>>(cv, depth, featH, out);
}